// Round 11
// baseline (228.173 us; speedup 1.0000x reference)
//
#include <hip/hip_runtime.h>
#include <hip/hip_bf16.h>
#include <type_traits>

// ---------------------------------------------------------------------------
// CausalSelfAttention: x[4,2048,1024] f32, w_qkv[3072,1024], w_out[1024,1024]
// Pipeline: cvt(bf16) -> GEMM qkv -> causal flash attn -> GEMM out (f32)
// ---------------------------------------------------------------------------

typedef __attribute__((ext_vector_type(8))) short bf16x8;
typedef __attribute__((ext_vector_type(4))) float f32x4;

#define LDS_AS(p) ((__attribute__((address_space(3))) void*)(p))
#define GLB_AS(p) ((const __attribute__((address_space(1))) void*)(p))

// ------------------- fp32 -> bf16 (all three inputs, one launch) -----------
__global__ __launch_bounds__(256) void cvt3_f32_bf16(const float* __restrict__ a,
                                                     const float* __restrict__ b,
                                                     const float* __restrict__ c,
                                                     __hip_bfloat16* __restrict__ oa,
                                                     __hip_bfloat16* __restrict__ ob,
                                                     __hip_bfloat16* __restrict__ oc,
                                                     int na4, int nb4, int nc4) {
  int i = blockIdx.x * 256 + threadIdx.x;
  const float* in; __hip_bfloat16* out;
  if (i < na4) { in = a; out = oa; }
  else if (i < na4 + nb4) { in = b; out = ob; i -= na4; }
  else if (i < na4 + nb4 + nc4) { in = c; out = oc; i -= na4 + nb4; }
  else return;
  float4 v = reinterpret_cast<const float4*>(in)[i];
  __hip_bfloat16 b0 = __float2bfloat16(v.x);
  __hip_bfloat16 b1 = __float2bfloat16(v.y);
  __hip_bfloat16 b2 = __float2bfloat16(v.z);
  __hip_bfloat16 b3 = __float2bfloat16(v.w);
  ushort4 u;
  u.x = *reinterpret_cast<unsigned short*>(&b0);
  u.y = *reinterpret_cast<unsigned short*>(&b1);
  u.z = *reinterpret_cast<unsigned short*>(&b2);
  u.w = *reinterpret_cast<unsigned short*>(&b3);
  reinterpret_cast<ushort4*>(out)[i] = u;
}

// --------------------- GEMM: C[M,N] = A[M,K] * B[N,K]^T --------------------
// m97 structure + single-barrier LDS double-buffer + T1 XCD-band swizzle:
// 1-D grid; each XCD owns one contiguous band of 8 m-blocks x all n-blocks
// (A-band 2MB resident in its 4MB L2; each B panel fetched once per XCD).
// Requires (M/128)%8==0 and grid%8==0 (true for both call sites).
template <typename TOUT>
__global__ __launch_bounds__(256) void gemm_bt(const __hip_bfloat16* __restrict__ A,
                                               const __hip_bfloat16* __restrict__ B,
                                               TOUT* __restrict__ C,
                                               int M, int N, int K) {
  __shared__ __hip_bfloat16 As[2][128 * 64];
  __shared__ __hip_bfloat16 Bs[2][128 * 64];
  const int tid = threadIdx.x;
  const int lane = tid & 63;
  const int wid = tid >> 6;
  const int l15 = lane & 15, l4 = lane >> 4;

  // ---- XCD-band block swizzle (T1) ----
  const int nbn = N >> 7;
  const int per = gridDim.x >> 3;              // blocks per XCD
  const int g = (blockIdx.x & 7) * per + (blockIdx.x >> 3);
  const int bandsz = nbn << 3;                 // 8 m-blocks x nbn
  const int band = g / bandsz;
  const int w = g - band * bandsz;
  const int m0 = (band * 8 + (w & 7)) * 128;   // m fastest within band
  const int n0 = (w >> 3) * 128;

  const int wr = (wid >> 1) * 64;
  const int wc = (wid & 1) * 64;
  const int NT = K >> 6;  // K-steps of 64
  f32x4 acc[4][4] = {};

  // ---- prologue: stage tile 0 into buf 0 ----
#pragma unroll
  for (int i = 0; i < 4; ++i) {
    const int slot = i * 256 + tid;
    const int row = slot >> 3, c8 = slot & 7;
    __builtin_amdgcn_global_load_lds(GLB_AS(A + (size_t)(m0 + row) * K + c8 * 8),
                                     LDS_AS((char*)As[0] + slot * 16), 16, 0, 0);
    __builtin_amdgcn_global_load_lds(GLB_AS(B + (size_t)(n0 + row) * K + c8 * 8),
                                     LDS_AS((char*)Bs[0] + slot * 16), 16, 0, 0);
  }
  __syncthreads();  // compiler drains vmcnt before barrier: tile 0 landed

  int cur = 0;
  for (int t = 0; t < NT; ++t) {
    // ---- issue loads for tile t+1 into buf[cur^1] (overlap with compute) --
    if (t + 1 < NT) {
      const int kt = (t + 1) << 6;
#pragma unroll
      for (int i = 0; i < 4; ++i) {
        const int slot = i * 256 + tid;
        const int row = slot >> 3, c8 = slot & 7;
        __builtin_amdgcn_global_load_lds(GLB_AS(A + (size_t)(m0 + row) * K + kt + c8 * 8),
                                         LDS_AS((char*)As[cur ^ 1] + slot * 16), 16, 0, 0);
        __builtin_amdgcn_global_load_lds(GLB_AS(B + (size_t)(n0 + row) * K + kt + c8 * 8),
                                         LDS_AS((char*)Bs[cur ^ 1] + slot * 16), 16, 0, 0);
      }
    }
    // ---- compute tile t from buf[cur] ----
#pragma unroll
    for (int kk = 0; kk < 2; ++kk) {
      bf16x8 af[4], bfr[4];
#pragma unroll
      for (int mi = 0; mi < 4; ++mi)
        af[mi] = *reinterpret_cast<const bf16x8*>(&As[cur][(wr + mi * 16 + l15) * 64 + kk * 32 + l4 * 8]);
#pragma unroll
      for (int ni = 0; ni < 4; ++ni)
        bfr[ni] = *reinterpret_cast<const bf16x8*>(&Bs[cur][(wc + ni * 16 + l15) * 64 + kk * 32 + l4 * 8]);
#pragma unroll
      for (int mi = 0; mi < 4; ++mi)
#pragma unroll
        for (int ni = 0; ni < 4; ++ni)
          acc[mi][ni] = __builtin_amdgcn_mfma_f32_16x16x32_bf16(af[mi], bfr[ni], acc[mi][ni], 0, 0, 0);
    }
    // ---- one drain+barrier per K-step: tile t+1 landed, buf[cur] free ----
    if (t + 1 < NT) __syncthreads();
    cur ^= 1;
  }
#pragma unroll
  for (int mi = 0; mi < 4; ++mi)
#pragma unroll
    for (int ni = 0; ni < 4; ++ni)
#pragma unroll
      for (int j = 0; j < 4; ++j) {
        const int m = m0 + wr + mi * 16 + l4 * 4 + j;
        const int n = n0 + wc + ni * 16 + l15;
        if constexpr (std::is_same<TOUT, float>::value)
          C[(size_t)m * N + n] = acc[mi][ni][j];
        else
          C[(size_t)m * N + n] = __float2bfloat16(acc[mi][ni][j]);
      }
}

// --------------------------- causal flash attn -----------------------------
// R6 config (best measured: 119 us). 512 threads = 8 waves; waves 0-3 own
// 256-row q-tile x, waves 4-7 own 7-x (uniform per-SIMD work); 4 Q-frags/wave;
// grid 256 = 1 block/CU. __launch_bounds__(512,2) -> 128-VGPR cap, no spill
// (R7 evidence: (512,4) caps at 64 VGPR -> catastrophic spills).
// Both matmuls swapped so q=lane&15 is lane-local; LDS K/V double-buffered,
// ONE barrier per tile; Q prescaled by 1/sqrt(64)*log2e; defer-max THR=8.
__global__ __launch_bounds__(512, 2) void attn_causal(const __hip_bfloat16* __restrict__ qkv,
                                                      __hip_bfloat16* __restrict__ o) {
  constexpr int T = 2048, F = 3072, C = 1024;
  __shared__ __hip_bfloat16 Ks[2][64 * 72];     // K tile  [kv][d], pad 72
  __shared__ __hip_bfloat16 Vts[2][64 * 72];    // V^T tile [d][kv], pad 72
  __shared__ __hip_bfloat16 Ps[8][16 * 72];     // per-wave P [q][kv], pad 72
  const int tid = threadIdx.x;
  const int wid = tid >> 6, lane = tid & 63;
  const int l15 = lane & 15, l4 = lane >> 4;
  const int x = blockIdx.x, h = blockIdx.y, b = blockIdx.z;
  const int qt = (wid < 4) ? x : (7 - x);       // this wave's 256-row q-tile
  const int nt = 4 * (7 - x) + 4;               // KV tiles staged by the block
  const int tmax = 4 * qt + (wid & 3);          // this wave's diagonal tile
  const int hoff = h * 64;
  const __hip_bfloat16* base = qkv + (size_t)b * T * F;
  const int Q0 = qt * 256 + (wid & 3) * 64;     // wave's first q row

  constexpr float SC = 0.125f * 1.44269504088896f;  // 1/sqrt(64) * log2(e)

  // Q frags (B operand), prescaled by SC -> S comes out in log2 domain
  bf16x8 aq[4][2];
#pragma unroll
  for (int f = 0; f < 4; ++f)
#pragma unroll
    for (int kk = 0; kk < 2; ++kk) {
      bf16x8 q = *reinterpret_cast<const bf16x8*>(base + (size_t)(Q0 + f * 16 + l15) * F + hoff + kk * 32 + l4 * 8);
#pragma unroll
      for (int e = 0; e < 8; ++e) {
        const unsigned short raw = (unsigned short)q[e];
        const float fv = __uint_as_float((unsigned)raw << 16) * SC;
        __hip_bfloat16 qs = __float2bfloat16(fv);
        q[e] = *reinterpret_cast<short*>(&qs);
      }
      aq[f][kk] = q;
    }

  f32x4 acc[4][4] = {};   // [frag][di]: O[q=Q0+f*16+l15][d=di*16+l4*4+j]
  float mrun[4], lrun[4];
#pragma unroll
  for (int f = 0; f < 4; ++f) { mrun[f] = -1e30f; lrun[f] = 0.f; }

  // staging roles: waves 0-3 stage V (2 rows/thread), waves 4-7 stage K
  const int sV = tid;        // valid when wid<4: r2=sV>>3, c8=sV&7
  const int sK = tid - 256;  // valid when wid>=4
  bf16x8 sreg0, sreg1;
  if (wid < 4) {
    const size_t vr = (size_t)(2 * (sV >> 3)) * F + hoff + 2 * C + (sV & 7) * 8;
    sreg0 = *reinterpret_cast<const bf16x8*>(base + vr);
    sreg1 = *reinterpret_cast<const bf16x8*>(base + vr + F);
  } else {
    sreg0 = *reinterpret_cast<const bf16x8*>(base + (size_t)(sK >> 3) * F + hoff + C + (sK & 7) * 8);
    sreg1 = *reinterpret_cast<const bf16x8*>(base + (size_t)(32 + (sK >> 3)) * F + hoff + C + (sK & 7) * 8);
  }

  for (int t = 0; t < nt; ++t) {
    const int cur = t & 1;
    // ---- write staged tile t (in sregs) into buf[cur] ----
    if (wid < 4) {
      // pack V pair-dwords, rotate by c8 (bank-spread; static idx only)
      const unsigned short* a0 = reinterpret_cast<const unsigned short*>(&sreg0);
      const unsigned short* a1 = reinterpret_cast<const unsigned short*>(&sreg1);
      const int c8 = sV & 7, r2 = sV >> 3;
      unsigned pk[8], tw[8], pkr[8];
#pragma unroll
      for (int j = 0; j < 8; ++j) pk[j] = (unsigned)a0[j] | ((unsigned)a1[j] << 16);
#pragma unroll
      for (int j = 0; j < 8; ++j) tw[j] = (c8 & 4) ? pk[(j + 4) & 7] : pk[j];
#pragma unroll
      for (int j = 0; j < 8; ++j) pkr[j] = (c8 & 2) ? tw[(j + 2) & 7] : tw[j];
#pragma unroll
      for (int j = 0; j < 8; ++j) tw[j] = (c8 & 1) ? pkr[(j + 1) & 7] : pkr[j];
#pragma unroll
      for (int jj = 0; jj < 8; ++jj) {
        const int d = c8 * 8 + ((jj + c8) & 7);
        *reinterpret_cast<unsigned*>(&Vts[cur][d * 72 + 2 * r2]) = tw[jj];
      }
    } else {
      *reinterpret_cast<bf16x8*>(&Ks[cur][(sK >> 3) * 72 + (sK & 7) * 8]) = sreg0;
      *reinterpret_cast<bf16x8*>(&Ks[cur][(32 + (sK >> 3)) * 72 + (sK & 7) * 8]) = sreg1;
    }
    __syncthreads();   // buf[cur] visible; buf[cur^1] free for next iter
    // ---- issue loads for tile t+1 (land during compute below) ----
    if (t + 1 < nt) {
      const int kn = (t + 1) * 64;
      if (wid < 4) {
        const size_t vr = (size_t)(kn + 2 * (sV >> 3)) * F + hoff + 2 * C + (sV & 7) * 8;
        sreg0 = *reinterpret_cast<const bf16x8*>(base + vr);
        sreg1 = *reinterpret_cast<const bf16x8*>(base + vr + F);
      } else {
        sreg0 = *reinterpret_cast<const bf16x8*>(base + (size_t)(kn + (sK >> 3)) * F + hoff + C + (sK & 7) * 8);
        sreg1 = *reinterpret_cast<const bf16x8*>(base + (size_t)(kn + 32 + (sK >> 3)) * F + hoff + C + (sK & 7) * 8);
      }
    }
    if (t > tmax) continue;  // wave-uniform skip; barrier is at loop top
    const bool diag = (t == tmax);

    // ---- hoist K / V^T fragments (shared by all 4 q-frags) ----
    bf16x8 kf[4][2], vf[4][2];
#pragma unroll
    for (int kt = 0; kt < 4; ++kt)
#pragma unroll
      for (int kk = 0; kk < 2; ++kk)
        kf[kt][kk] = *reinterpret_cast<const bf16x8*>(&Ks[cur][(kt * 16 + l15) * 72 + kk * 32 + l4 * 8]);
#pragma unroll
    for (int di = 0; di < 4; ++di)
#pragma unroll
      for (int kk = 0; kk < 2; ++kk)
        vf[di][kk] = *reinterpret_cast<const bf16x8*>(&Vts[cur][(di * 16 + l15) * 72 + kk * 32 + l4 * 8]);

    __hip_bfloat16* pw = Ps[wid];
#pragma unroll
    for (int f = 0; f < 4; ++f) {
      // ---- S^T = K Q^T (log2 domain; Q prescaled) ----
      f32x4 s[4];
#pragma unroll
      for (int kt = 0; kt < 4; ++kt) {
        f32x4 z = {};
        z = __builtin_amdgcn_mfma_f32_16x16x32_bf16(kf[kt][0], aq[f][0], z, 0, 0, 0);
        z = __builtin_amdgcn_mfma_f32_16x16x32_bf16(kf[kt][1], aq[f][1], z, 0, 0, 0);
        s[kt] = z;
      }
      // ---- causal mask (diag tile only; pure select) ----
      if (diag) {
        const int ql = f * 16 + l15;
#pragma unroll
        for (int kt = 0; kt < 4; ++kt)
#pragma unroll
          for (int j = 0; j < 4; ++j) {
            const int kvl = kt * 16 + l4 * 4 + j;
            s[kt][j] = (kvl <= ql) ? s[kt][j] : -1e30f;
          }
      }

      // ---- online softmax (max tree + 2 shuffles) ----
      float t0 = fmaxf(fmaxf(s[0][0], s[0][1]), s[0][2]);
      float t1 = fmaxf(fmaxf(s[0][3], s[1][0]), s[1][1]);
      float t2 = fmaxf(fmaxf(s[1][2], s[1][3]), s[2][0]);
      float t3 = fmaxf(fmaxf(s[2][1], s[2][2]), s[2][3]);
      float t4 = fmaxf(fmaxf(s[3][0], s[3][1]), s[3][2]);
      float mt = fmaxf(fmaxf(fmaxf(t0, t1), fmaxf(t2, t3)), fmaxf(t4, s[3][3]));
      mt = fmaxf(mt, __shfl_xor(mt, 16, 64));
      mt = fmaxf(mt, __shfl_xor(mt, 32, 64));
      // defer-max: if max grew by <= 8 (log2), keep old max, skip rescale
      const bool defer = __all(mt <= mrun[f] + 8.f);
      const float mnew = defer ? mrun[f] : fmaxf(mrun[f], mt);
      float rs = 0.f;
#pragma unroll
      for (int kt = 0; kt < 4; ++kt) {
        float p0 = exp2f(s[kt][0] - mnew), p1 = exp2f(s[kt][1] - mnew);
        float p2 = exp2f(s[kt][2] - mnew), p3 = exp2f(s[kt][3] - mnew);
        s[kt][0] = p0; s[kt][1] = p1; s[kt][2] = p2; s[kt][3] = p3;
        rs += (p0 + p1) + (p2 + p3);
      }
      rs += __shfl_xor(rs, 16, 64);
      rs += __shfl_xor(rs, 32, 64);
      if (defer) {
        lrun[f] += rs;
      } else {
        const float sco = exp2f(mrun[f] - mnew);
        lrun[f] = lrun[f] * sco + rs;
        mrun[f] = mnew;
#pragma unroll
        for (int di = 0; di < 4; ++di) acc[f][di] *= sco;
      }

      // ---- P -> per-wave LDS (cvt_pk + 4x ds_write_b64) -> B-frags ----
#pragma unroll
      for (int kt = 0; kt < 4; ++kt) {
        unsigned w0, w1;
        asm("v_cvt_pk_bf16_f32 %0, %1, %2" : "=v"(w0) : "v"(s[kt][0]), "v"(s[kt][1]));
        asm("v_cvt_pk_bf16_f32 %0, %1, %2" : "=v"(w1) : "v"(s[kt][2]), "v"(s[kt][3]));
        unsigned long long dw = (unsigned long long)w0 | ((unsigned long long)w1 << 32);
        *reinterpret_cast<unsigned long long*>(&pw[l15 * 72 + kt * 16 + l4 * 4]) = dw;
      }
      // Ordering fence: writes above / reads below alias via different TBAA
      // types; force program order + drain DS queue (rule-18 family).
      asm volatile("s_waitcnt lgkmcnt(0)" ::: "memory");
      bf16x8 pa0 = *reinterpret_cast<const bf16x8*>(pw + l15 * 72 + l4 * 8);
      bf16x8 pa1 = *reinterpret_cast<const bf16x8*>(pw + l15 * 72 + 32 + l4 * 8);

      // ---- O^T += V^T P^T ----
#pragma unroll
      for (int di = 0; di < 4; ++di) {
        acc[f][di] = __builtin_amdgcn_mfma_f32_16x16x32_bf16(vf[di][0], pa0, acc[f][di], 0, 0, 0);
        acc[f][di] = __builtin_amdgcn_mfma_f32_16x16x32_bf16(vf[di][1], pa1, acc[f][di], 0, 0, 0);
      }
    }
  }

  // ---- normalize + write: lane has O[q=Q0+f*16+l15][d=di*16+l4*4+(0..3)] ---
#pragma unroll
  for (int f = 0; f < 4; ++f) {
    const float inv = 1.0f / lrun[f];
    __hip_bfloat16* op = o + (size_t)((size_t)b * T + Q0 + f * 16 + l15) * C + hoff;
#pragma unroll
    for (int di = 0; di < 4; ++di) {
      ushort4 u;
      __hip_bfloat16 e0 = __float2bfloat16(acc[f][di][0] * inv);
      __hip_bfloat16 e1 = __float2bfloat16(acc[f][di][1] * inv);
      __hip_bfloat16 e2 = __float2bfloat16(acc[f][di][2] * inv);
      __hip_bfloat16 e3 = __float2bfloat16(acc[f][di][3] * inv);
      u.x = *reinterpret_cast<unsigned short*>(&e0);
      u.y = *reinterpret_cast<unsigned short*>(&e1);
      u.z = *reinterpret_cast<unsigned short*>(&e2);
      u.w = *reinterpret_cast<unsigned short*>(&e3);
      *reinterpret_cast<ushort4*>(op + di * 16 + l4 * 4) = u;
    }
  }
}

// ------------------------------- launcher ----------------------------------
extern "C" void kernel_launch(void* const* d_in, const int* in_sizes, int n_in,
                              void* d_out, int out_size, void* d_ws, size_t ws_size,
                              hipStream_t stream) {
  const float* x = (const float*)d_in[0];
  const float* w_qkv = (const float*)d_in[1];
  const float* w_out = (const float*)d_in[2];
  float* out = (float*)d_out;

  constexpr int B = 4, T = 2048, C = 1024, F = 3 * C;
  constexpr int M = B * T;

  __hip_bfloat16* xb = (__hip_bfloat16*)d_ws;            // M*C
  __hip_bfloat16* wqkvb = xb + (size_t)M * C;            // F*C
  __hip_bfloat16* woutb = wqkvb + (size_t)F * C;         // C*C
  __hip_bfloat16* qkvb = woutb + (size_t)C * C;          // M*F
  __hip_bfloat16* attnb = qkvb + (size_t)M * F;          // M*C

  constexpr int na4 = M * C / 4, nb4 = F * C / 4, nc4 = C * C / 4;
  cvt3_f32_bf16<<<(na4 + nb4 + nc4 + 255) / 256, 256, 0, stream>>>(
      x, w_qkv, w_out, xb, wqkvb, woutb, na4, nb4, nc4);

  // 1-D grids (XCD-band swizzle inside the kernel)
  gemm_bt<__hip_bfloat16><<<(M / 128) * (F / 128), 256, 0, stream>>>(xb, wqkvb, qkvb, M, F, C);

  attn_causal<<<dim3(4, 16, B), 512, 0, stream>>>(qkvb, attnb);

  gemm_bt<float><<<(M / 128) * (C / 128), 256, 0, stream>>>(attnb, woutb, out, M, C, C);
}

// Round 12
// 221.686 us; speedup vs baseline: 1.0293x; 1.0293x over previous
//
#include <hip/hip_runtime.h>
#include <hip/hip_bf16.h>
#include <type_traits>

// ---------------------------------------------------------------------------
// CausalSelfAttention: x[4,2048,1024] f32, w_qkv[3072,1024], w_out[1024,1024]
// Pipeline: cvt(bf16) -> GEMM qkv (256^2 counted-vmcnt) -> causal flash attn
//           -> GEMM out (128^2) (f32)
// ---------------------------------------------------------------------------

typedef __attribute__((ext_vector_type(8))) short bf16x8;
typedef __attribute__((ext_vector_type(4))) float f32x4;

#define LDS_AS(p) ((__attribute__((address_space(3))) void*)(p))
#define GLB_AS(p) ((const __attribute__((address_space(1))) void*)(p))

// ------------------- fp32 -> bf16 (all three inputs, one launch) -----------
__global__ __launch_bounds__(256) void cvt3_f32_bf16(const float* __restrict__ a,
                                                     const float* __restrict__ b,
                                                     const float* __restrict__ c,
                                                     __hip_bfloat16* __restrict__ oa,
                                                     __hip_bfloat16* __restrict__ ob,
                                                     __hip_bfloat16* __restrict__ oc,
                                                     int na4, int nb4, int nc4) {
  int i = blockIdx.x * 256 + threadIdx.x;
  const float* in; __hip_bfloat16* out;
  if (i < na4) { in = a; out = oa; }
  else if (i < na4 + nb4) { in = b; out = ob; i -= na4; }
  else if (i < na4 + nb4 + nc4) { in = c; out = oc; i -= na4 + nb4; }
  else return;
  float4 v = reinterpret_cast<const float4*>(in)[i];
  __hip_bfloat16 b0 = __float2bfloat16(v.x);
  __hip_bfloat16 b1 = __float2bfloat16(v.y);
  __hip_bfloat16 b2 = __float2bfloat16(v.z);
  __hip_bfloat16 b3 = __float2bfloat16(v.w);
  ushort4 u;
  u.x = *reinterpret_cast<unsigned short*>(&b0);
  u.y = *reinterpret_cast<unsigned short*>(&b1);
  u.z = *reinterpret_cast<unsigned short*>(&b2);
  u.w = *reinterpret_cast<unsigned short*>(&b3);
  reinterpret_cast<ushort4*>(out)[i] = u;
}

// ---------------- GEMM 256^2: C[M,N] = A[M,K] * B[N,K]^T, bf16 out ---------
// 8 waves (2M x 4N), per-wave 128x64 out. 2-K-tile LDS dbuf (128 KB).
// Counted vmcnt: loads for tile t+2 issued at end of tile t (prefetch dist 2);
// entry waits vmcnt(8) (tile t landed, t+1 still in flight) -- raw s_barrier
// (NOT __syncthreads, which force-drains vmcnt to 0 and kills the pipeline).
// T2 row-XOR swizzle on 16B slots (both sides: inverse-swz global source +
// swz ds_read) -> ds_read_b128 spreads 8 lanes/bank-group = conflict-free.
__global__ __launch_bounds__(512, 1) void gemm_bt256(const __hip_bfloat16* __restrict__ A,
                                                     const __hip_bfloat16* __restrict__ B,
                                                     __hip_bfloat16* __restrict__ C,
                                                     int M, int N, int K) {
  __shared__ __hip_bfloat16 As[2][256 * 64];
  __shared__ __hip_bfloat16 Bs[2][256 * 64];
  const int tid = threadIdx.x;               // 0..511
  const int lane = tid & 63;
  const int wid = tid >> 6;                  // 0..7
  const int l15 = lane & 15, l4 = lane >> 4;
  const int wr = wid >> 2;                   // 0..1  (M half)
  const int wc = wid & 3;                    // 0..3  (N quarter)
  const int m0 = blockIdx.x * 256, n0 = blockIdx.y * 256;
  const int NT = K >> 6;
  f32x4 acc[8][4] = {};

  // staging: 4 loads per matrix per thread per K-tile. slot = i*512+tid,
  // row = slot>>3, c8 = slot&7. LDS dest LINEAR (slot*16); global source
  // col-slot = c8 ^ (row&7)  (inverse swizzle; involution).
#define STAGE256(buf, kt)                                                            \
  do {                                                                               \
    _Pragma("unroll")                                                                \
    for (int i_ = 0; i_ < 4; ++i_) {                                                 \
      const int slot_ = i_ * 512 + tid;                                              \
      const int row_ = slot_ >> 3, c8_ = slot_ & 7;                                  \
      const int gc_ = (c8_ ^ (row_ & 7)) * 8;                                        \
      __builtin_amdgcn_global_load_lds(                                              \
          GLB_AS(A + (size_t)(m0 + row_) * K + (kt) + gc_),                          \
          LDS_AS((char*)As[buf] + slot_ * 16), 16, 0, 0);                            \
      __builtin_amdgcn_global_load_lds(                                              \
          GLB_AS(B + (size_t)(n0 + row_) * K + (kt) + gc_),                          \
          LDS_AS((char*)Bs[buf] + slot_ * 16), 16, 0, 0);                            \
    }                                                                                \
  } while (0)

  STAGE256(0, 0);
  if (NT > 1) STAGE256(1, 64);

  for (int t = 0; t < NT; ++t) {
    const int cur = t & 1;
    // wait own-wave slice of tile t (8 loads); tile t+1's 8 stay in flight
    if (t < NT - 1) asm volatile("s_waitcnt vmcnt(8)" ::: "memory");
    else            asm volatile("s_waitcnt vmcnt(0)" ::: "memory");
    __builtin_amdgcn_s_barrier();            // all waves' slices landed
    asm volatile("" ::: "memory");           // no ds_read hoists above barrier

    // 4 quadrant phases: 64 rows x 32 cols each = 16 MFMA
#pragma unroll
    for (int q = 0; q < 4; ++q) {
      const int mbase = wr * 128 + (q & 1) * 64;
      const int nbase = wc * 64 + (q >> 1) * 32;
      bf16x8 af[4][2], bfr[2][2];
#pragma unroll
      for (int mi = 0; mi < 4; ++mi)
#pragma unroll
        for (int kk = 0; kk < 2; ++kk) {
          const int r = mbase + mi * 16 + l15;
          af[mi][kk] = *reinterpret_cast<const bf16x8*>(
              &As[cur][r * 64 + (((kk * 4 + l4) ^ (r & 7)) * 8)]);
        }
#pragma unroll
      for (int nj = 0; nj < 2; ++nj)
#pragma unroll
        for (int kk = 0; kk < 2; ++kk) {
          const int r = nbase + nj * 16 + l15;
          bfr[nj][kk] = *reinterpret_cast<const bf16x8*>(
              &Bs[cur][r * 64 + (((kk * 4 + l4) ^ (r & 7)) * 8)]);
        }
      __builtin_amdgcn_s_setprio(1);
#pragma unroll
      for (int mi = 0; mi < 4; ++mi)
#pragma unroll
        for (int nj = 0; nj < 2; ++nj) {
          acc[(q & 1) * 4 + mi][(q >> 1) * 2 + nj] = __builtin_amdgcn_mfma_f32_16x16x32_bf16(
              af[mi][0], bfr[nj][0], acc[(q & 1) * 4 + mi][(q >> 1) * 2 + nj], 0, 0, 0);
          acc[(q & 1) * 4 + mi][(q >> 1) * 2 + nj] = __builtin_amdgcn_mfma_f32_16x16x32_bf16(
              af[mi][1], bfr[nj][1], acc[(q & 1) * 4 + mi][(q >> 1) * 2 + nj], 0, 0, 0);
        }
      __builtin_amdgcn_s_setprio(0);
    }
    asm volatile("" ::: "memory");
    __builtin_amdgcn_s_barrier();            // all waves done reading buf[cur]
    asm volatile("" ::: "memory");
    if (t + 2 < NT) STAGE256(cur, (t + 2) << 6);  // refill consumed buffer
  }
#undef STAGE256

  // epilogue: m = m0 + wr*128 + mi*16 + l4*4 + j, n = n0 + wc*64 + ni*16 + l15
#pragma unroll
  for (int mi = 0; mi < 8; ++mi)
#pragma unroll
    for (int ni = 0; ni < 4; ++ni)
#pragma unroll
      for (int j = 0; j < 4; ++j) {
        const int m = m0 + wr * 128 + mi * 16 + l4 * 4 + j;
        const int n = n0 + wc * 64 + ni * 16 + l15;
        C[(size_t)m * N + n] = __float2bfloat16(acc[mi][ni][j]);
      }
}

// --------------------- GEMM 128^2 (for the out-proj) -----------------------
template <typename TOUT>
__global__ __launch_bounds__(256) void gemm_bt(const __hip_bfloat16* __restrict__ A,
                                               const __hip_bfloat16* __restrict__ B,
                                               TOUT* __restrict__ C,
                                               int M, int N, int K) {
  __shared__ __hip_bfloat16 As[2][128 * 64];
  __shared__ __hip_bfloat16 Bs[2][128 * 64];
  const int tid = threadIdx.x;
  const int lane = tid & 63;
  const int wid = tid >> 6;
  const int l15 = lane & 15, l4 = lane >> 4;
  const int m0 = blockIdx.x * 128, n0 = blockIdx.y * 128;
  const int wr = (wid >> 1) * 64;
  const int wc = (wid & 1) * 64;
  const int NT = K >> 6;
  f32x4 acc[4][4] = {};

#pragma unroll
  for (int i = 0; i < 4; ++i) {
    const int slot = i * 256 + tid;
    const int row = slot >> 3, c8 = slot & 7;
    __builtin_amdgcn_global_load_lds(GLB_AS(A + (size_t)(m0 + row) * K + c8 * 8),
                                     LDS_AS((char*)As[0] + slot * 16), 16, 0, 0);
    __builtin_amdgcn_global_load_lds(GLB_AS(B + (size_t)(n0 + row) * K + c8 * 8),
                                     LDS_AS((char*)Bs[0] + slot * 16), 16, 0, 0);
  }
  __syncthreads();

  int cur = 0;
  for (int t = 0; t < NT; ++t) {
    if (t + 1 < NT) {
      const int kt = (t + 1) << 6;
#pragma unroll
      for (int i = 0; i < 4; ++i) {
        const int slot = i * 256 + tid;
        const int row = slot >> 3, c8 = slot & 7;
        __builtin_amdgcn_global_load_lds(GLB_AS(A + (size_t)(m0 + row) * K + kt + c8 * 8),
                                         LDS_AS((char*)As[cur ^ 1] + slot * 16), 16, 0, 0);
        __builtin_amdgcn_global_load_lds(GLB_AS(B + (size_t)(n0 + row) * K + kt + c8 * 8),
                                         LDS_AS((char*)Bs[cur ^ 1] + slot * 16), 16, 0, 0);
      }
    }
#pragma unroll
    for (int kk = 0; kk < 2; ++kk) {
      bf16x8 af[4], bfr[4];
#pragma unroll
      for (int mi = 0; mi < 4; ++mi)
        af[mi] = *reinterpret_cast<const bf16x8*>(&As[cur][(wr + mi * 16 + l15) * 64 + kk * 32 + l4 * 8]);
#pragma unroll
      for (int ni = 0; ni < 4; ++ni)
        bfr[ni] = *reinterpret_cast<const bf16x8*>(&Bs[cur][(wc + ni * 16 + l15) * 64 + kk * 32 + l4 * 8]);
#pragma unroll
      for (int mi = 0; mi < 4; ++mi)
#pragma unroll
        for (int ni = 0; ni < 4; ++ni)
          acc[mi][ni] = __builtin_amdgcn_mfma_f32_16x16x32_bf16(af[mi], bfr[ni], acc[mi][ni], 0, 0, 0);
    }
    if (t + 1 < NT) __syncthreads();
    cur ^= 1;
  }
#pragma unroll
  for (int mi = 0; mi < 4; ++mi)
#pragma unroll
    for (int ni = 0; ni < 4; ++ni)
#pragma unroll
      for (int j = 0; j < 4; ++j) {
        const int m = m0 + wr + mi * 16 + l4 * 4 + j;
        const int n = n0 + wc + ni * 16 + l15;
        if constexpr (std::is_same<TOUT, float>::value)
          C[(size_t)m * N + n] = acc[mi][ni][j];
        else
          C[(size_t)m * N + n] = __float2bfloat16(acc[mi][ni][j]);
      }
}

// --------------------------- causal flash attn -----------------------------
// R6 config (best measured: 119 us). 512 threads = 8 waves; waves 0-3 own
// 256-row q-tile x, waves 4-7 own 7-x (uniform per-SIMD work); 4 Q-frags/wave;
// grid 256 = 1 block/CU. __launch_bounds__(512,2) -> 128-VGPR cap, no spill
// (R7 evidence: (512,4) caps at 64 VGPR -> catastrophic spills).
__global__ __launch_bounds__(512, 2) void attn_causal(const __hip_bfloat16* __restrict__ qkv,
                                                      __hip_bfloat16* __restrict__ o) {
  constexpr int T = 2048, F = 3072, C = 1024;
  __shared__ __hip_bfloat16 Ks[2][64 * 72];
  __shared__ __hip_bfloat16 Vts[2][64 * 72];
  __shared__ __hip_bfloat16 Ps[8][16 * 72];
  const int tid = threadIdx.x;
  const int wid = tid >> 6, lane = tid & 63;
  const int l15 = lane & 15, l4 = lane >> 4;
  const int x = blockIdx.x, h = blockIdx.y, b = blockIdx.z;
  const int qt = (wid < 4) ? x : (7 - x);
  const int nt = 4 * (7 - x) + 4;
  const int tmax = 4 * qt + (wid & 3);
  const int hoff = h * 64;
  const __hip_bfloat16* base = qkv + (size_t)b * T * F;
  const int Q0 = qt * 256 + (wid & 3) * 64;

  constexpr float SC = 0.125f * 1.44269504088896f;

  bf16x8 aq[4][2];
#pragma unroll
  for (int f = 0; f < 4; ++f)
#pragma unroll
    for (int kk = 0; kk < 2; ++kk) {
      bf16x8 q = *reinterpret_cast<const bf16x8*>(base + (size_t)(Q0 + f * 16 + l15) * F + hoff + kk * 32 + l4 * 8);
#pragma unroll
      for (int e = 0; e < 8; ++e) {
        const unsigned short raw = (unsigned short)q[e];
        const float fv = __uint_as_float((unsigned)raw << 16) * SC;
        __hip_bfloat16 qs = __float2bfloat16(fv);
        q[e] = *reinterpret_cast<short*>(&qs);
      }
      aq[f][kk] = q;
    }

  f32x4 acc[4][4] = {};
  float mrun[4], lrun[4];
#pragma unroll
  for (int f = 0; f < 4; ++f) { mrun[f] = -1e30f; lrun[f] = 0.f; }

  const int sV = tid;
  const int sK = tid - 256;
  bf16x8 sreg0, sreg1;
  if (wid < 4) {
    const size_t vr = (size_t)(2 * (sV >> 3)) * F + hoff + 2 * C + (sV & 7) * 8;
    sreg0 = *reinterpret_cast<const bf16x8*>(base + vr);
    sreg1 = *reinterpret_cast<const bf16x8*>(base + vr + F);
  } else {
    sreg0 = *reinterpret_cast<const bf16x8*>(base + (size_t)(sK >> 3) * F + hoff + C + (sK & 7) * 8);
    sreg1 = *reinterpret_cast<const bf16x8*>(base + (size_t)(32 + (sK >> 3)) * F + hoff + C + (sK & 7) * 8);
  }

  for (int t = 0; t < nt; ++t) {
    const int cur = t & 1;
    if (wid < 4) {
      const unsigned short* a0 = reinterpret_cast<const unsigned short*>(&sreg0);
      const unsigned short* a1 = reinterpret_cast<const unsigned short*>(&sreg1);
      const int c8 = sV & 7, r2 = sV >> 3;
      unsigned pk[8], tw[8], pkr[8];
#pragma unroll
      for (int j = 0; j < 8; ++j) pk[j] = (unsigned)a0[j] | ((unsigned)a1[j] << 16);
#pragma unroll
      for (int j = 0; j < 8; ++j) tw[j] = (c8 & 4) ? pk[(j + 4) & 7] : pk[j];
#pragma unroll
      for (int j = 0; j < 8; ++j) pkr[j] = (c8 & 2) ? tw[(j + 2) & 7] : tw[j];
#pragma unroll
      for (int j = 0; j < 8; ++j) tw[j] = (c8 & 1) ? pkr[(j + 1) & 7] : pkr[j];
#pragma unroll
      for (int jj = 0; jj < 8; ++jj) {
        const int d = c8 * 8 + ((jj + c8) & 7);
        *reinterpret_cast<unsigned*>(&Vts[cur][d * 72 + 2 * r2]) = tw[jj];
      }
    } else {
      *reinterpret_cast<bf16x8*>(&Ks[cur][(sK >> 3) * 72 + (sK & 7) * 8]) = sreg0;
      *reinterpret_cast<bf16x8*>(&Ks[cur][(32 + (sK >> 3)) * 72 + (sK & 7) * 8]) = sreg1;
    }
    __syncthreads();
    if (t + 1 < nt) {
      const int kn = (t + 1) * 64;
      if (wid < 4) {
        const size_t vr = (size_t)(kn + 2 * (sV >> 3)) * F + hoff + 2 * C + (sV & 7) * 8;
        sreg0 = *reinterpret_cast<const bf16x8*>(base + vr);
        sreg1 = *reinterpret_cast<const bf16x8*>(base + vr + F);
      } else {
        sreg0 = *reinterpret_cast<const bf16x8*>(base + (size_t)(kn + (sK >> 3)) * F + hoff + C + (sK & 7) * 8);
        sreg1 = *reinterpret_cast<const bf16x8*>(base + (size_t)(kn + 32 + (sK >> 3)) * F + hoff + C + (sK & 7) * 8);
      }
    }
    if (t > tmax) continue;
    const bool diag = (t == tmax);

    bf16x8 kf[4][2], vf[4][2];
#pragma unroll
    for (int kt = 0; kt < 4; ++kt)
#pragma unroll
      for (int kk = 0; kk < 2; ++kk)
        kf[kt][kk] = *reinterpret_cast<const bf16x8*>(&Ks[cur][(kt * 16 + l15) * 72 + kk * 32 + l4 * 8]);
#pragma unroll
    for (int di = 0; di < 4; ++di)
#pragma unroll
      for (int kk = 0; kk < 2; ++kk)
        vf[di][kk] = *reinterpret_cast<const bf16x8*>(&Vts[cur][(di * 16 + l15) * 72 + kk * 32 + l4 * 8]);

    __hip_bfloat16* pw = Ps[wid];
#pragma unroll
    for (int f = 0; f < 4; ++f) {
      f32x4 s[4];
#pragma unroll
      for (int kt = 0; kt < 4; ++kt) {
        f32x4 z = {};
        z = __builtin_amdgcn_mfma_f32_16x16x32_bf16(kf[kt][0], aq[f][0], z, 0, 0, 0);
        z = __builtin_amdgcn_mfma_f32_16x16x32_bf16(kf[kt][1], aq[f][1], z, 0, 0, 0);
        s[kt] = z;
      }
      if (diag) {
        const int ql = f * 16 + l15;
#pragma unroll
        for (int kt = 0; kt < 4; ++kt)
#pragma unroll
          for (int j = 0; j < 4; ++j) {
            const int kvl = kt * 16 + l4 * 4 + j;
            s[kt][j] = (kvl <= ql) ? s[kt][j] : -1e30f;
          }
      }

      float t0 = fmaxf(fmaxf(s[0][0], s[0][1]), s[0][2]);
      float t1 = fmaxf(fmaxf(s[0][3], s[1][0]), s[1][1]);
      float t2 = fmaxf(fmaxf(s[1][2], s[1][3]), s[2][0]);
      float t3 = fmaxf(fmaxf(s[2][1], s[2][2]), s[2][3]);
      float t4 = fmaxf(fmaxf(s[3][0], s[3][1]), s[3][2]);
      float mt = fmaxf(fmaxf(fmaxf(t0, t1), fmaxf(t2, t3)), fmaxf(t4, s[3][3]));
      mt = fmaxf(mt, __shfl_xor(mt, 16, 64));
      mt = fmaxf(mt, __shfl_xor(mt, 32, 64));
      const bool defer = __all(mt <= mrun[f] + 8.f);
      const float mnew = defer ? mrun[f] : fmaxf(mrun[f], mt);
      float rs = 0.f;
#pragma unroll
      for (int kt = 0; kt < 4; ++kt) {
        float p0 = exp2f(s[kt][0] - mnew), p1 = exp2f(s[kt][1] - mnew);
        float p2 = exp2f(s[kt][2] - mnew), p3 = exp2f(s[kt][3] - mnew);
        s[kt][0] = p0; s[kt][1] = p1; s[kt][2] = p2; s[kt][3] = p3;
        rs += (p0 + p1) + (p2 + p3);
      }
      rs += __shfl_xor(rs, 16, 64);
      rs += __shfl_xor(rs, 32, 64);
      if (defer) {
        lrun[f] += rs;
      } else {
        const float sco = exp2f(mrun[f] - mnew);
        lrun[f] = lrun[f] * sco + rs;
        mrun[f] = mnew;
#pragma unroll
        for (int di = 0; di < 4; ++di) acc[f][di] *= sco;
      }

#pragma unroll
      for (int kt = 0; kt < 4; ++kt) {
        unsigned w0, w1;
        asm("v_cvt_pk_bf16_f32 %0, %1, %2" : "=v"(w0) : "v"(s[kt][0]), "v"(s[kt][1]));
        asm("v_cvt_pk_bf16_f32 %0, %1, %2" : "=v"(w1) : "v"(s[kt][2]), "v"(s[kt][3]));
        unsigned long long dw = (unsigned long long)w0 | ((unsigned long long)w1 << 32);
        *reinterpret_cast<unsigned long long*>(&pw[l15 * 72 + kt * 16 + l4 * 4]) = dw;
      }
      asm volatile("s_waitcnt lgkmcnt(0)" ::: "memory");
      bf16x8 pa0 = *reinterpret_cast<const bf16x8*>(pw + l15 * 72 + l4 * 8);
      bf16x8 pa1 = *reinterpret_cast<const bf16x8*>(pw + l15 * 72 + 32 + l4 * 8);

#pragma unroll
      for (int di = 0; di < 4; ++di) {
        acc[f][di] = __builtin_amdgcn_mfma_f32_16x16x32_bf16(vf[di][0], pa0, acc[f][di], 0, 0, 0);
        acc[f][di] = __builtin_amdgcn_mfma_f32_16x16x32_bf16(vf[di][1], pa1, acc[f][di], 0, 0, 0);
      }
    }
  }

#pragma unroll
  for (int f = 0; f < 4; ++f) {
    const float inv = 1.0f / lrun[f];
    __hip_bfloat16* op = o + (size_t)((size_t)b * T + Q0 + f * 16 + l15) * C + hoff;
#pragma unroll
    for (int di = 0; di < 4; ++di) {
      ushort4 u;
      __hip_bfloat16 e0 = __float2bfloat16(acc[f][di][0] * inv);
      __hip_bfloat16 e1 = __float2bfloat16(acc[f][di][1] * inv);
      __hip_bfloat16 e2 = __float2bfloat16(acc[f][di][2] * inv);
      __hip_bfloat16 e3 = __float2bfloat16(acc[f][di][3] * inv);
      u.x = *reinterpret_cast<unsigned short*>(&e0);
      u.y = *reinterpret_cast<unsigned short*>(&e1);
      u.z = *reinterpret_cast<unsigned short*>(&e2);
      u.w = *reinterpret_cast<unsigned short*>(&e3);
      *reinterpret_cast<ushort4*>(op + di * 16 + l4 * 4) = u;
    }
  }
}

// ------------------------------- launcher ----------------------------------
extern "C" void kernel_launch(void* const* d_in, const int* in_sizes, int n_in,
                              void* d_out, int out_size, void* d_ws, size_t ws_size,
                              hipStream_t stream) {
  const float* x = (const float*)d_in[0];
  const float* w_qkv = (const float*)d_in[1];
  const float* w_out = (const float*)d_in[2];
  float* out = (float*)d_out;

  constexpr int B = 4, T = 2048, C = 1024, F = 3 * C;
  constexpr int M = B * T;

  __hip_bfloat16* xb = (__hip_bfloat16*)d_ws;            // M*C
  __hip_bfloat16* wqkvb = xb + (size_t)M * C;            // F*C
  __hip_bfloat16* woutb = wqkvb + (size_t)F * C;         // C*C
  __hip_bfloat16* qkvb = woutb + (size_t)C * C;          // M*F
  __hip_bfloat16* attnb = qkvb + (size_t)M * F;          // M*C

  constexpr int na4 = M * C / 4, nb4 = F * C / 4, nc4 = C * C / 4;
  cvt3_f32_bf16<<<(na4 + nb4 + nc4 + 255) / 256, 256, 0, stream>>>(
      x, w_qkv, w_out, xb, wqkvb, woutb, na4, nb4, nc4);

  gemm_bt256<<<dim3(M / 256, F / 256), 512, 0, stream>>>(xb, wqkvb, qkvb, M, F, C);

  attn_causal<<<dim3(4, 16, B), 512, 0, stream>>>(qkvb, attnb);

  gemm_bt<float><<<dim3(M / 128, C / 128), 256, 0, stream>>>(attnb, woutb, out, M, C, C);
}

// Round 13
// 219.568 us; speedup vs baseline: 1.0392x; 1.0096x over previous
//
#include <hip/hip_runtime.h>
#include <hip/hip_bf16.h>
#include <type_traits>

// ---------------------------------------------------------------------------
// CausalSelfAttention: x[4,2048,1024] f32, w_qkv[3072,1024], w_out[1024,1024]
// Pipeline: cvt(bf16) -> GEMM qkv (256^2 counted-vmcnt) -> causal flash attn
//           -> GEMM out (256x128 counted-vmcnt, f32)
// ---------------------------------------------------------------------------

typedef __attribute__((ext_vector_type(8))) short bf16x8;
typedef __attribute__((ext_vector_type(4))) float f32x4;

#define LDS_AS(p) ((__attribute__((address_space(3))) void*)(p))
#define GLB_AS(p) ((const __attribute__((address_space(1))) void*)(p))

// ------------------- fp32 -> bf16 (all three inputs, one launch) -----------
__global__ __launch_bounds__(256) void cvt3_f32_bf16(const float* __restrict__ a,
                                                     const float* __restrict__ b,
                                                     const float* __restrict__ c,
                                                     __hip_bfloat16* __restrict__ oa,
                                                     __hip_bfloat16* __restrict__ ob,
                                                     __hip_bfloat16* __restrict__ oc,
                                                     int na4, int nb4, int nc4) {
  const int ntot = na4 + nb4 + nc4;
  for (int i = blockIdx.x * 256 + threadIdx.x; i < ntot; i += gridDim.x * 256) {
    int j = i;
    const float* in; __hip_bfloat16* out;
    if (j < na4) { in = a; out = oa; }
    else if (j < na4 + nb4) { in = b; out = ob; j -= na4; }
    else { in = c; out = oc; j -= na4 + nb4; }
    float4 v = reinterpret_cast<const float4*>(in)[j];
    __hip_bfloat16 b0 = __float2bfloat16(v.x);
    __hip_bfloat16 b1 = __float2bfloat16(v.y);
    __hip_bfloat16 b2 = __float2bfloat16(v.z);
    __hip_bfloat16 b3 = __float2bfloat16(v.w);
    ushort4 u;
    u.x = *reinterpret_cast<unsigned short*>(&b0);
    u.y = *reinterpret_cast<unsigned short*>(&b1);
    u.z = *reinterpret_cast<unsigned short*>(&b2);
    u.w = *reinterpret_cast<unsigned short*>(&b3);
    reinterpret_cast<ushort4*>(out)[j] = u;
  }
}

// ---------------- GEMM 256^2: C[M,N] = A[M,K] * B[N,K]^T, bf16 out ---------
// 8 waves (2M x 4N), per-wave 128x64 out. 2-K-tile LDS dbuf (128 KB).
// Counted vmcnt (prefetch dist 2, entry wait vmcnt(8), raw s_barrier).
// T2 row-XOR swizzle on 16B slots (inverse-swz global source + swz ds_read).
__global__ __launch_bounds__(512, 1) void gemm_bt256(const __hip_bfloat16* __restrict__ A,
                                                     const __hip_bfloat16* __restrict__ B,
                                                     __hip_bfloat16* __restrict__ C,
                                                     int M, int N, int K) {
  __shared__ __hip_bfloat16 As[2][256 * 64];
  __shared__ __hip_bfloat16 Bs[2][256 * 64];
  const int tid = threadIdx.x;
  const int lane = tid & 63;
  const int wid = tid >> 6;
  const int l15 = lane & 15, l4 = lane >> 4;
  const int wr = wid >> 2;
  const int wc = wid & 3;
  const int m0 = blockIdx.x * 256, n0 = blockIdx.y * 256;
  const int NT = K >> 6;
  f32x4 acc[8][4] = {};

#define STAGE256(buf, kt)                                                            \
  do {                                                                               \
    _Pragma("unroll")                                                                \
    for (int i_ = 0; i_ < 4; ++i_) {                                                 \
      const int slot_ = i_ * 512 + tid;                                              \
      const int row_ = slot_ >> 3, c8_ = slot_ & 7;                                  \
      const int gc_ = (c8_ ^ (row_ & 7)) * 8;                                        \
      __builtin_amdgcn_global_load_lds(                                              \
          GLB_AS(A + (size_t)(m0 + row_) * K + (kt) + gc_),                          \
          LDS_AS((char*)As[buf] + slot_ * 16), 16, 0, 0);                            \
      __builtin_amdgcn_global_load_lds(                                              \
          GLB_AS(B + (size_t)(n0 + row_) * K + (kt) + gc_),                          \
          LDS_AS((char*)Bs[buf] + slot_ * 16), 16, 0, 0);                            \
    }                                                                                \
  } while (0)

  STAGE256(0, 0);
  if (NT > 1) STAGE256(1, 64);

  for (int t = 0; t < NT; ++t) {
    const int cur = t & 1;
    if (t < NT - 1) asm volatile("s_waitcnt vmcnt(8)" ::: "memory");
    else            asm volatile("s_waitcnt vmcnt(0)" ::: "memory");
    __builtin_amdgcn_s_barrier();
    asm volatile("" ::: "memory");

#pragma unroll
    for (int q = 0; q < 4; ++q) {
      const int mbase = wr * 128 + (q & 1) * 64;
      const int nbase = wc * 64 + (q >> 1) * 32;
      bf16x8 af[4][2], bfr[2][2];
#pragma unroll
      for (int mi = 0; mi < 4; ++mi)
#pragma unroll
        for (int kk = 0; kk < 2; ++kk) {
          const int r = mbase + mi * 16 + l15;
          af[mi][kk] = *reinterpret_cast<const bf16x8*>(
              &As[cur][r * 64 + (((kk * 4 + l4) ^ (r & 7)) * 8)]);
        }
#pragma unroll
      for (int nj = 0; nj < 2; ++nj)
#pragma unroll
        for (int kk = 0; kk < 2; ++kk) {
          const int r = nbase + nj * 16 + l15;
          bfr[nj][kk] = *reinterpret_cast<const bf16x8*>(
              &Bs[cur][r * 64 + (((kk * 4 + l4) ^ (r & 7)) * 8)]);
        }
      __builtin_amdgcn_s_setprio(1);
#pragma unroll
      for (int mi = 0; mi < 4; ++mi)
#pragma unroll
        for (int nj = 0; nj < 2; ++nj) {
          acc[(q & 1) * 4 + mi][(q >> 1) * 2 + nj] = __builtin_amdgcn_mfma_f32_16x16x32_bf16(
              af[mi][0], bfr[nj][0], acc[(q & 1) * 4 + mi][(q >> 1) * 2 + nj], 0, 0, 0);
          acc[(q & 1) * 4 + mi][(q >> 1) * 2 + nj] = __builtin_amdgcn_mfma_f32_16x16x32_bf16(
              af[mi][1], bfr[nj][1], acc[(q & 1) * 4 + mi][(q >> 1) * 2 + nj], 0, 0, 0);
        }
      __builtin_amdgcn_s_setprio(0);
    }
    asm volatile("" ::: "memory");
    __builtin_amdgcn_s_barrier();
    asm volatile("" ::: "memory");
    if (t + 2 < NT) STAGE256(cur, (t + 2) << 6);
  }
#undef STAGE256

#pragma unroll
  for (int mi = 0; mi < 8; ++mi)
#pragma unroll
    for (int ni = 0; ni < 4; ++ni)
#pragma unroll
      for (int j = 0; j < 4; ++j) {
        const int m = m0 + wr * 128 + mi * 16 + l4 * 4 + j;
        const int n = n0 + wc * 64 + ni * 16 + l15;
        C[(size_t)m * N + n] = __float2bfloat16(acc[mi][ni][j]);
      }
}

// ------------- GEMM 256x128: C[M,N] = A[M,K]*B[N,K]^T, f32 out -------------
// 8 waves (4M x 2N), per-wave 64x64 (identical math to the proven 128^2
// kernel). Counted vmcnt: per-thread loads/stage L = 4(A)+2(B) = 6 ->
// steady-state entry wait vmcnt(6); prefetch dist 2; raw s_barrier; T2
// both-sides swizzle. Grid (M/256)x(N/128) = 256 blocks = 1/CU for GEMM2.
__global__ __launch_bounds__(512, 1) void gemm_bt256x128f(const __hip_bfloat16* __restrict__ A,
                                                          const __hip_bfloat16* __restrict__ B,
                                                          float* __restrict__ C,
                                                          int M, int N, int K) {
  __shared__ __hip_bfloat16 As[2][256 * 64];   // 64 KB
  __shared__ __hip_bfloat16 Bs[2][128 * 64];   // 32 KB
  const int tid = threadIdx.x;
  const int lane = tid & 63;
  const int wid = tid >> 6;
  const int l15 = lane & 15, l4 = lane >> 4;
  const int wr = (wid >> 1) * 64;              // 0,64,128,192 (M)
  const int wc = (wid & 1) * 64;               // 0,64 (N)
  const int m0 = blockIdx.x * 256, n0 = blockIdx.y * 128;
  const int NT = K >> 6;
  f32x4 acc[4][4] = {};

#define STAGE2(buf, kt)                                                              \
  do {                                                                               \
    _Pragma("unroll")                                                                \
    for (int i_ = 0; i_ < 4; ++i_) {                                                 \
      const int slot_ = i_ * 512 + tid;                                              \
      const int row_ = slot_ >> 3, c8_ = slot_ & 7;                                  \
      const int gc_ = (c8_ ^ (row_ & 7)) * 8;                                        \
      __builtin_amdgcn_global_load_lds(                                              \
          GLB_AS(A + (size_t)(m0 + row_) * K + (kt) + gc_),                          \
          LDS_AS((char*)As[buf] + slot_ * 16), 16, 0, 0);                            \
    }                                                                                \
    _Pragma("unroll")                                                                \
    for (int i_ = 0; i_ < 2; ++i_) {                                                 \
      const int slot_ = i_ * 512 + tid;                                              \
      const int row_ = slot_ >> 3, c8_ = slot_ & 7;                                  \
      const int gc_ = (c8_ ^ (row_ & 7)) * 8;                                        \
      __builtin_amdgcn_global_load_lds(                                              \
          GLB_AS(B + (size_t)(n0 + row_) * K + (kt) + gc_),                          \
          LDS_AS((char*)Bs[buf] + slot_ * 16), 16, 0, 0);                            \
    }                                                                                \
  } while (0)

  STAGE2(0, 0);
  if (NT > 1) STAGE2(1, 64);

  for (int t = 0; t < NT; ++t) {
    const int cur = t & 1;
    if (t < NT - 1) asm volatile("s_waitcnt vmcnt(6)" ::: "memory");
    else            asm volatile("s_waitcnt vmcnt(0)" ::: "memory");
    __builtin_amdgcn_s_barrier();
    asm volatile("" ::: "memory");

#pragma unroll
    for (int kk = 0; kk < 2; ++kk) {
      bf16x8 af[4], bfr[4];
#pragma unroll
      for (int mi = 0; mi < 4; ++mi) {
        const int r = wr + mi * 16 + l15;
        af[mi] = *reinterpret_cast<const bf16x8*>(
            &As[cur][r * 64 + (((kk * 4 + l4) ^ (r & 7)) * 8)]);
      }
#pragma unroll
      for (int ni = 0; ni < 4; ++ni) {
        const int r = wc + ni * 16 + l15;
        bfr[ni] = *reinterpret_cast<const bf16x8*>(
            &Bs[cur][r * 64 + (((kk * 4 + l4) ^ (r & 7)) * 8)]);
      }
      __builtin_amdgcn_s_setprio(1);
#pragma unroll
      for (int mi = 0; mi < 4; ++mi)
#pragma unroll
        for (int ni = 0; ni < 4; ++ni)
          acc[mi][ni] = __builtin_amdgcn_mfma_f32_16x16x32_bf16(af[mi], bfr[ni], acc[mi][ni], 0, 0, 0);
      __builtin_amdgcn_s_setprio(0);
    }
    asm volatile("" ::: "memory");
    __builtin_amdgcn_s_barrier();
    asm volatile("" ::: "memory");
    if (t + 2 < NT) STAGE2(cur, (t + 2) << 6);
  }
#undef STAGE2

#pragma unroll
  for (int mi = 0; mi < 4; ++mi)
#pragma unroll
    for (int ni = 0; ni < 4; ++ni)
#pragma unroll
      for (int j = 0; j < 4; ++j) {
        const int m = m0 + wr + mi * 16 + l4 * 4 + j;
        const int n = n0 + wc + ni * 16 + l15;
        C[(size_t)m * N + n] = acc[mi][ni][j];
      }
}

// --------------------------- causal flash attn -----------------------------
// R6 config (best measured: 119 us). 512 threads = 8 waves; waves 0-3 own
// 256-row q-tile x, waves 4-7 own 7-x (uniform per-SIMD work); 4 Q-frags/wave;
// grid 256 = 1 block/CU. __launch_bounds__(512,2) -> 128-VGPR cap, no spill.
__global__ __launch_bounds__(512, 2) void attn_causal(const __hip_bfloat16* __restrict__ qkv,
                                                      __hip_bfloat16* __restrict__ o) {
  constexpr int T = 2048, F = 3072, C = 1024;
  __shared__ __hip_bfloat16 Ks[2][64 * 72];
  __shared__ __hip_bfloat16 Vts[2][64 * 72];
  __shared__ __hip_bfloat16 Ps[8][16 * 72];
  const int tid = threadIdx.x;
  const int wid = tid >> 6, lane = tid & 63;
  const int l15 = lane & 15, l4 = lane >> 4;
  const int x = blockIdx.x, h = blockIdx.y, b = blockIdx.z;
  const int qt = (wid < 4) ? x : (7 - x);
  const int nt = 4 * (7 - x) + 4;
  const int tmax = 4 * qt + (wid & 3);
  const int hoff = h * 64;
  const __hip_bfloat16* base = qkv + (size_t)b * T * F;
  const int Q0 = qt * 256 + (wid & 3) * 64;

  constexpr float SC = 0.125f * 1.44269504088896f;

  bf16x8 aq[4][2];
#pragma unroll
  for (int f = 0; f < 4; ++f)
#pragma unroll
    for (int kk = 0; kk < 2; ++kk) {
      bf16x8 q = *reinterpret_cast<const bf16x8*>(base + (size_t)(Q0 + f * 16 + l15) * F + hoff + kk * 32 + l4 * 8);
#pragma unroll
      for (int e = 0; e < 8; ++e) {
        const unsigned short raw = (unsigned short)q[e];
        const float fv = __uint_as_float((unsigned)raw << 16) * SC;
        __hip_bfloat16 qs = __float2bfloat16(fv);
        q[e] = *reinterpret_cast<short*>(&qs);
      }
      aq[f][kk] = q;
    }

  f32x4 acc[4][4] = {};
  float mrun[4], lrun[4];
#pragma unroll
  for (int f = 0; f < 4; ++f) { mrun[f] = -1e30f; lrun[f] = 0.f; }

  const int sV = tid;
  const int sK = tid - 256;
  bf16x8 sreg0, sreg1;
  if (wid < 4) {
    const size_t vr = (size_t)(2 * (sV >> 3)) * F + hoff + 2 * C + (sV & 7) * 8;
    sreg0 = *reinterpret_cast<const bf16x8*>(base + vr);
    sreg1 = *reinterpret_cast<const bf16x8*>(base + vr + F);
  } else {
    sreg0 = *reinterpret_cast<const bf16x8*>(base + (size_t)(sK >> 3) * F + hoff + C + (sK & 7) * 8);
    sreg1 = *reinterpret_cast<const bf16x8*>(base + (size_t)(32 + (sK >> 3)) * F + hoff + C + (sK & 7) * 8);
  }

  for (int t = 0; t < nt; ++t) {
    const int cur = t & 1;
    if (wid < 4) {
      const unsigned short* a0 = reinterpret_cast<const unsigned short*>(&sreg0);
      const unsigned short* a1 = reinterpret_cast<const unsigned short*>(&sreg1);
      const int c8 = sV & 7, r2 = sV >> 3;
      unsigned pk[8], tw[8], pkr[8];
#pragma unroll
      for (int j = 0; j < 8; ++j) pk[j] = (unsigned)a0[j] | ((unsigned)a1[j] << 16);
#pragma unroll
      for (int j = 0; j < 8; ++j) tw[j] = (c8 & 4) ? pk[(j + 4) & 7] : pk[j];
#pragma unroll
      for (int j = 0; j < 8; ++j) pkr[j] = (c8 & 2) ? tw[(j + 2) & 7] : tw[j];
#pragma unroll
      for (int j = 0; j < 8; ++j) tw[j] = (c8 & 1) ? pkr[(j + 1) & 7] : pkr[j];
#pragma unroll
      for (int jj = 0; jj < 8; ++jj) {
        const int d = c8 * 8 + ((jj + c8) & 7);
        *reinterpret_cast<unsigned*>(&Vts[cur][d * 72 + 2 * r2]) = tw[jj];
      }
    } else {
      *reinterpret_cast<bf16x8*>(&Ks[cur][(sK >> 3) * 72 + (sK & 7) * 8]) = sreg0;
      *reinterpret_cast<bf16x8*>(&Ks[cur][(32 + (sK >> 3)) * 72 + (sK & 7) * 8]) = sreg1;
    }
    __syncthreads();
    if (t + 1 < nt) {
      const int kn = (t + 1) * 64;
      if (wid < 4) {
        const size_t vr = (size_t)(kn + 2 * (sV >> 3)) * F + hoff + 2 * C + (sV & 7) * 8;
        sreg0 = *reinterpret_cast<const bf16x8*>(base + vr);
        sreg1 = *reinterpret_cast<const bf16x8*>(base + vr + F);
      } else {
        sreg0 = *reinterpret_cast<const bf16x8*>(base + (size_t)(kn + (sK >> 3)) * F + hoff + C + (sK & 7) * 8);
        sreg1 = *reinterpret_cast<const bf16x8*>(base + (size_t)(kn + 32 + (sK >> 3)) * F + hoff + C + (sK & 7) * 8);
      }
    }
    if (t > tmax) continue;
    const bool diag = (t == tmax);

    bf16x8 kf[4][2], vf[4][2];
#pragma unroll
    for (int kt = 0; kt < 4; ++kt)
#pragma unroll
      for (int kk = 0; kk < 2; ++kk)
        kf[kt][kk] = *reinterpret_cast<const bf16x8*>(&Ks[cur][(kt * 16 + l15) * 72 + kk * 32 + l4 * 8]);
#pragma unroll
    for (int di = 0; di < 4; ++di)
#pragma unroll
      for (int kk = 0; kk < 2; ++kk)
        vf[di][kk] = *reinterpret_cast<const bf16x8*>(&Vts[cur][(di * 16 + l15) * 72 + kk * 32 + l4 * 8]);

    __hip_bfloat16* pw = Ps[wid];
#pragma unroll
    for (int f = 0; f < 4; ++f) {
      f32x4 s[4];
#pragma unroll
      for (int kt = 0; kt < 4; ++kt) {
        f32x4 z = {};
        z = __builtin_amdgcn_mfma_f32_16x16x32_bf16(kf[kt][0], aq[f][0], z, 0, 0, 0);
        z = __builtin_amdgcn_mfma_f32_16x16x32_bf16(kf[kt][1], aq[f][1], z, 0, 0, 0);
        s[kt] = z;
      }
      if (diag) {
        const int ql = f * 16 + l15;
#pragma unroll
        for (int kt = 0; kt < 4; ++kt)
#pragma unroll
          for (int j = 0; j < 4; ++j) {
            const int kvl = kt * 16 + l4 * 4 + j;
            s[kt][j] = (kvl <= ql) ? s[kt][j] : -1e30f;
          }
      }

      float t0 = fmaxf(fmaxf(s[0][0], s[0][1]), s[0][2]);
      float t1 = fmaxf(fmaxf(s[0][3], s[1][0]), s[1][1]);
      float t2 = fmaxf(fmaxf(s[1][2], s[1][3]), s[2][0]);
      float t3 = fmaxf(fmaxf(s[2][1], s[2][2]), s[2][3]);
      float t4 = fmaxf(fmaxf(s[3][0], s[3][1]), s[3][2]);
      float mt = fmaxf(fmaxf(fmaxf(t0, t1), fmaxf(t2, t3)), fmaxf(t4, s[3][3]));
      mt = fmaxf(mt, __shfl_xor(mt, 16, 64));
      mt = fmaxf(mt, __shfl_xor(mt, 32, 64));
      const bool defer = __all(mt <= mrun[f] + 8.f);
      const float mnew = defer ? mrun[f] : fmaxf(mrun[f], mt);
      float rs = 0.f;
#pragma unroll
      for (int kt = 0; kt < 4; ++kt) {
        float p0 = exp2f(s[kt][0] - mnew), p1 = exp2f(s[kt][1] - mnew);
        float p2 = exp2f(s[kt][2] - mnew), p3 = exp2f(s[kt][3] - mnew);
        s[kt][0] = p0; s[kt][1] = p1; s[kt][2] = p2; s[kt][3] = p3;
        rs += (p0 + p1) + (p2 + p3);
      }
      rs += __shfl_xor(rs, 16, 64);
      rs += __shfl_xor(rs, 32, 64);
      if (defer) {
        lrun[f] += rs;
      } else {
        const float sco = exp2f(mrun[f] - mnew);
        lrun[f] = lrun[f] * sco + rs;
        mrun[f] = mnew;
#pragma unroll
        for (int di = 0; di < 4; ++di) acc[f][di] *= sco;
      }

#pragma unroll
      for (int kt = 0; kt < 4; ++kt) {
        unsigned w0, w1;
        asm("v_cvt_pk_bf16_f32 %0, %1, %2" : "=v"(w0) : "v"(s[kt][0]), "v"(s[kt][1]));
        asm("v_cvt_pk_bf16_f32 %0, %1, %2" : "=v"(w1) : "v"(s[kt][2]), "v"(s[kt][3]));
        unsigned long long dw = (unsigned long long)w0 | ((unsigned long long)w1 << 32);
        *reinterpret_cast<unsigned long long*>(&pw[l15 * 72 + kt * 16 + l4 * 4]) = dw;
      }
      asm volatile("s_waitcnt lgkmcnt(0)" ::: "memory");
      bf16x8 pa0 = *reinterpret_cast<const bf16x8*>(pw + l15 * 72 + l4 * 8);
      bf16x8 pa1 = *reinterpret_cast<const bf16x8*>(pw + l15 * 72 + 32 + l4 * 8);

#pragma unroll
      for (int di = 0; di < 4; ++di) {
        acc[f][di] = __builtin_amdgcn_mfma_f32_16x16x32_bf16(vf[di][0], pa0, acc[f][di], 0, 0, 0);
        acc[f][di] = __builtin_amdgcn_mfma_f32_16x16x32_bf16(vf[di][1], pa1, acc[f][di], 0, 0, 0);
      }
    }
  }

#pragma unroll
  for (int f = 0; f < 4; ++f) {
    const float inv = 1.0f / lrun[f];
    __hip_bfloat16* op = o + (size_t)((size_t)b * T + Q0 + f * 16 + l15) * C + hoff;
#pragma unroll
    for (int di = 0; di < 4; ++di) {
      ushort4 u;
      __hip_bfloat16 e0 = __float2bfloat16(acc[f][di][0] * inv);
      __hip_bfloat16 e1 = __float2bfloat16(acc[f][di][1] * inv);
      __hip_bfloat16 e2 = __float2bfloat16(acc[f][di][2] * inv);
      __hip_bfloat16 e3 = __float2bfloat16(acc[f][di][3] * inv);
      u.x = *reinterpret_cast<unsigned short*>(&e0);
      u.y = *reinterpret_cast<unsigned short*>(&e1);
      u.z = *reinterpret_cast<unsigned short*>(&e2);
      u.w = *reinterpret_cast<unsigned short*>(&e3);
      *reinterpret_cast<ushort4*>(op + di * 16 + l4 * 4) = u;
    }
  }
}

// ------------------------------- launcher ----------------------------------
extern "C" void kernel_launch(void* const* d_in, const int* in_sizes, int n_in,
                              void* d_out, int out_size, void* d_ws, size_t ws_size,
                              hipStream_t stream) {
  const float* x = (const float*)d_in[0];
  const float* w_qkv = (const float*)d_in[1];
  const float* w_out = (const float*)d_in[2];
  float* out = (float*)d_out;

  constexpr int B = 4, T = 2048, C = 1024, F = 3 * C;
  constexpr int M = B * T;

  __hip_bfloat16* xb = (__hip_bfloat16*)d_ws;            // M*C
  __hip_bfloat16* wqkvb = xb + (size_t)M * C;            // F*C
  __hip_bfloat16* woutb = wqkvb + (size_t)F * C;         // C*C
  __hip_bfloat16* qkvb = woutb + (size_t)C * C;          // M*F
  __hip_bfloat16* attnb = qkvb + (size_t)M * F;          // M*C

  constexpr int na4 = M * C / 4, nb4 = F * C / 4, nc4 = C * C / 4;
  cvt3_f32_bf16<<<2048, 256, 0, stream>>>(x, w_qkv, w_out, xb, wqkvb, woutb, na4, nb4, nc4);

  gemm_bt256<<<dim3(M / 256, F / 256), 512, 0, stream>>>(xb, wqkvb, qkvb, M, F, C);

  attn_causal<<<dim3(4, 16, B), 512, 0, stream>>>(qkvb, attnb);

  gemm_bt256x128f<<<dim3(M / 256, C / 128), 512, 0, stream>>>(attnb, woutb, out, M, C, C);
}